// Round 1
// baseline (2010.859 us; speedup 1.0000x reference)
//
#include <hip/hip_runtime.h>
#include <hip/hip_bf16.h>

// 3-layer GCN, fp32 baseline.
// Pipeline:
//   deg histogram (atomics) -> dinv = rsqrt(deg+1)
//   L1: Bh = x@W1            ; Ba = Bh*dinv^2 + b1  (fused epilogue)
//       Ba += scatter-add over edges of Bh[src]*dinv[s]*dinv[d]   (atomics)
//   L2: Bh = relu(Ba)@W2     ; Ba = Bh*dinv^2 + b2
//       Ba += scatter-add
//   OUT: logits = relu(Ba)@W_out + b_out ; log_softmax per row (wave=64 = 64 logits)

#define FEAT 128
#define OUTF 64

__global__ void deg_kernel(const int* __restrict__ dst, float* __restrict__ deg, int E) {
    int i = blockIdx.x * blockDim.x + threadIdx.x;
    int stride = gridDim.x * blockDim.x;
    for (int e = i; e < E; e += stride)
        atomicAdd(&deg[dst[e]], 1.0f);
}

__global__ void dinv_kernel(const float* __restrict__ deg, float* __restrict__ dinv, int N) {
    int i = blockIdx.x * blockDim.x + threadIdx.x;
    if (i < N) dinv[i] = rsqrtf(deg[i] + 1.0f);
}

// Y[N,128] = (RELU ? relu(X) : X) @ W[128,128]
// Also writes A = Y*dinv^2 + bias  (self-loop init for the aggregation).
// W fully staged in LDS (64 KB). X read from global (broadcast within lane
// groups; L1/L2-resident). 256 threads, 32 rows/block, 4x4 register tile.
template <bool RELU>
__global__ __launch_bounds__(256) void gemm128_kernel(
        const float* __restrict__ X, const float* __restrict__ W,
        const float* __restrict__ bias, const float* __restrict__ dinv,
        float* __restrict__ Y, float* __restrict__ A, int N) {
    __shared__ float Ws[FEAT][FEAT];   // 64 KB
    int t = threadIdx.x;
    for (int i = t; i < FEAT * FEAT; i += 256)
        Ws[i >> 7][i & 127] = W[i];
    __syncthreads();

    int fg = t & 31;   // feature group -> f0 = fg*4
    int rg = t >> 5;   // row group 0..7 -> r0 = rg*4
    int f0 = fg * 4;
    int rbase = blockIdx.x * 32 + rg * 4;

    float acc[4][4] = {};
    #pragma unroll 1
    for (int k0 = 0; k0 < FEAT; k0 += 4) {
        float4 wv[4];
        #pragma unroll
        for (int kk = 0; kk < 4; ++kk)
            wv[kk] = *(const float4*)&Ws[k0 + kk][f0];
        #pragma unroll
        for (int r = 0; r < 4; ++r) {
            int row = rbase + r;
            float4 xv = make_float4(0.f, 0.f, 0.f, 0.f);
            if (row < N)
                xv = *(const float4*)(X + (size_t)row * FEAT + k0);
            if (RELU) {
                xv.x = fmaxf(xv.x, 0.f); xv.y = fmaxf(xv.y, 0.f);
                xv.z = fmaxf(xv.z, 0.f); xv.w = fmaxf(xv.w, 0.f);
            }
            acc[r][0] += xv.x * wv[0].x + xv.y * wv[1].x + xv.z * wv[2].x + xv.w * wv[3].x;
            acc[r][1] += xv.x * wv[0].y + xv.y * wv[1].y + xv.z * wv[2].y + xv.w * wv[3].y;
            acc[r][2] += xv.x * wv[0].z + xv.y * wv[1].z + xv.z * wv[2].z + xv.w * wv[3].z;
            acc[r][3] += xv.x * wv[0].w + xv.y * wv[1].w + xv.z * wv[2].w + xv.w * wv[3].w;
        }
    }

    // When X aliases A (layer 2), make sure every read in the block is done
    // before any thread writes A rows of this block.
    __syncthreads();

    float4 bb = *(const float4*)(bias + f0);
    #pragma unroll
    for (int r = 0; r < 4; ++r) {
        int row = rbase + r;
        if (row < N) {
            float di = dinv[row];
            float d2 = di * di;
            float4 h = make_float4(acc[r][0], acc[r][1], acc[r][2], acc[r][3]);
            *(float4*)(Y + (size_t)row * FEAT + f0) = h;
            float4 a = make_float4(h.x * d2 + bb.x, h.y * d2 + bb.y,
                                   h.z * d2 + bb.z, h.w * d2 + bb.w);
            *(float4*)(A + (size_t)row * FEAT + f0) = a;
        }
    }
}

// Edge-parallel scatter-add: A[dst] += H[src] * dinv[src]*dinv[dst]
__global__ __launch_bounds__(256) void agg_kernel(
        const int* __restrict__ src, const int* __restrict__ dst,
        const float* __restrict__ dinv, const float* __restrict__ H,
        float* __restrict__ A, int E) {
    int e = blockIdx.x * 2 + (threadIdx.x >> 7);
    if (e >= E) return;
    int f = threadIdx.x & 127;
    int s = src[e], d = dst[e];
    float w = dinv[s] * dinv[d];
    atomicAdd(A + (size_t)d * FEAT + f, H[(size_t)s * FEAT + f] * w);
}

// logits = relu(H) @ Wout[128,64] + bout ; out = log_softmax(logits)
// One wave (64 lanes) per row: lane j owns logit j. 4 waves/block, 4 rows/wave.
__global__ __launch_bounds__(256) void final_kernel(
        const float* __restrict__ H, const float* __restrict__ Wout,
        const float* __restrict__ bout, float* __restrict__ out, int N) {
    __shared__ float Ws[FEAT][OUTF];   // 32 KB
    int t = threadIdx.x;
    for (int i = t; i < FEAT * OUTF; i += 256)
        Ws[i >> 6][i & 63] = Wout[i];
    __syncthreads();

    int wave = t >> 6;
    int lane = t & 63;
    float bj = bout[lane];
    int rbase = blockIdx.x * 16 + wave * 4;

    for (int r = 0; r < 4; ++r) {
        int row = rbase + r;
        if (row >= N) continue;              // wave-uniform branch
        const float4* h4 = (const float4*)(H + (size_t)row * FEAT);
        float acc = bj;
        #pragma unroll
        for (int k4 = 0; k4 < FEAT / 4; ++k4) {
            float4 hv = h4[k4];
            hv.x = fmaxf(hv.x, 0.f); hv.y = fmaxf(hv.y, 0.f);
            hv.z = fmaxf(hv.z, 0.f); hv.w = fmaxf(hv.w, 0.f);
            acc += hv.x * Ws[4 * k4 + 0][lane] + hv.y * Ws[4 * k4 + 1][lane]
                 + hv.z * Ws[4 * k4 + 2][lane] + hv.w * Ws[4 * k4 + 3][lane];
        }
        // log-softmax across the 64 lanes of this wave
        float m = acc;
        #pragma unroll
        for (int o = 32; o > 0; o >>= 1) m = fmaxf(m, __shfl_xor(m, o));
        float ev = __expf(acc - m);
        float s = ev;
        #pragma unroll
        for (int o = 32; o > 0; o >>= 1) s += __shfl_xor(s, o);
        out[(size_t)row * OUTF + lane] = acc - m - __logf(s);
    }
}

extern "C" void kernel_launch(void* const* d_in, const int* in_sizes, int n_in,
                              void* d_out, int out_size, void* d_ws, size_t ws_size,
                              hipStream_t stream) {
    const float* x    = (const float*)d_in[0];
    const int*   ei   = (const int*)  d_in[1];
    const float* W1   = (const float*)d_in[2];
    const float* b1   = (const float*)d_in[3];
    const float* W2   = (const float*)d_in[4];
    const float* b2   = (const float*)d_in[5];
    const float* Wout = (const float*)d_in[6];
    const float* bout = (const float*)d_in[7];
    float* out = (float*)d_out;

    int N = in_sizes[0] / FEAT;
    int E = in_sizes[1] / 2;
    const int* srcp = ei;
    const int* dstp = ei + E;

    char* ws = (char*)d_ws;
    float* Bh   = (float*)ws;                                    // N*128
    float* Ba   = (float*)(ws + (size_t)N * FEAT * 4);           // N*128
    float* deg  = (float*)(ws + (size_t)N * FEAT * 8);           // N
    float* dinv = deg + N;                                       // N

    hipMemsetAsync(deg, 0, (size_t)N * sizeof(float), stream);
    deg_kernel<<<1024, 256, 0, stream>>>(dstp, deg, E);
    dinv_kernel<<<(N + 255) / 256, 256, 0, stream>>>(deg, dinv, N);

    int gemm_blocks = (N + 31) / 32;
    int agg_blocks  = (E + 1) / 2;

    // Layer 1
    gemm128_kernel<false><<<gemm_blocks, 256, 0, stream>>>(x, W1, b1, dinv, Bh, Ba, N);
    agg_kernel<<<agg_blocks, 256, 0, stream>>>(srcp, dstp, dinv, Bh, Ba, E);

    // Layer 2 (relu on input fused into GEMM load)
    gemm128_kernel<true><<<gemm_blocks, 256, 0, stream>>>(Ba, W2, b2, dinv, Bh, Ba, N);
    agg_kernel<<<agg_blocks, 256, 0, stream>>>(srcp, dstp, dinv, Bh, Ba, E);

    // Output layer + log_softmax
    final_kernel<<<(N + 15) / 16, 256, 0, stream>>>(Ba, Wout, bout, out, N);
}

// Round 2
// 794.008 us; speedup vs baseline: 2.5325x; 2.5325x over previous
//
#include <hip/hip_runtime.h>
#include <hip/hip_bf16.h>

// 3-layer GCN, fp32. Round 2: CSR gather aggregation (no fp32 atomics),
// register-pipelined 64x64 GEMM tiles.
//
// Pipeline:
//   degi histogram (int atomics) -> dinv = rsqrt(deg+1)
//   row_ptr = exclusive_scan(degi)  (3-kernel scan)
//   scatter edges into csr_src via atomic cursor
//   L1: Bh = x@W1        ; Ba = gather(Bh) + Bh*dinv^2 + b1
//   L2: Bh = relu(Ba)@W2 ; Ba = gather(Bh) + Bh*dinv^2 + b2
//   OUT: logits = relu(Ba)@Wout + bout ; log_softmax per row

#define FEAT 128
#define OUTF 64

__global__ __launch_bounds__(256) void deg_int_kernel(
        const int* __restrict__ dst, int* __restrict__ degi, int E) {
    int e = blockIdx.x * 256 + threadIdx.x;
    if (e < E) atomicAdd(&degi[dst[e]], 1);
}

__global__ __launch_bounds__(256) void dinv_kernel(
        const int* __restrict__ degi, float* __restrict__ dinv, int N) {
    int i = blockIdx.x * 256 + threadIdx.x;
    if (i < N) dinv[i] = rsqrtf((float)degi[i] + 1.0f);
}

// ---- 3-kernel exclusive scan over degi[N] -> row_ptr[N] (+ partials) ----
__global__ __launch_bounds__(256) void scan1_kernel(
        const int* __restrict__ degi, int* __restrict__ row_ptr,
        int* __restrict__ partial, int N) {
    int t = threadIdx.x;
    int base = blockIdx.x * 1024 + t * 4;
    int v[4];
    #pragma unroll
    for (int i = 0; i < 4; ++i) v[i] = (base + i < N) ? degi[base + i] : 0;
    int local = v[0] + v[1] + v[2] + v[3];
    int lane = t & 63, wv = t >> 6;
    int x = local;
    #pragma unroll
    for (int o = 1; o < 64; o <<= 1) {
        int y = __shfl_up(x, o);
        if (lane >= o) x += y;
    }
    __shared__ int wsum[4];
    if (lane == 63) wsum[wv] = x;
    __syncthreads();
    int woff = 0;
    for (int i = 0; i < wv; ++i) woff += wsum[i];
    int run = woff + x - local;   // exclusive prefix for this thread
    #pragma unroll
    for (int i = 0; i < 4; ++i) {
        if (base + i < N) row_ptr[base + i] = run;
        run += v[i];
    }
    if (t == 0) {
        // block total (after sync, wsum fully populated)
        partial[blockIdx.x] = 0;  // placeholder, fixed below
    }
    __syncthreads();
    if (t == 0) partial[blockIdx.x] = wsum[0] + wsum[1] + wsum[2] + wsum[3];
}

__global__ __launch_bounds__(256) void scan2_kernel(int* __restrict__ partial, int nb) {
    int t = threadIdx.x;
    int base = t * 4;
    int v[4];
    #pragma unroll
    for (int i = 0; i < 4; ++i) v[i] = (base + i < nb) ? partial[base + i] : 0;
    int local = v[0] + v[1] + v[2] + v[3];
    int lane = t & 63, wv = t >> 6;
    int x = local;
    #pragma unroll
    for (int o = 1; o < 64; o <<= 1) {
        int y = __shfl_up(x, o);
        if (lane >= o) x += y;
    }
    __shared__ int wsum[4];
    if (lane == 63) wsum[wv] = x;
    __syncthreads();
    int woff = 0;
    for (int i = 0; i < wv; ++i) woff += wsum[i];
    int run = woff + x - local;
    #pragma unroll
    for (int i = 0; i < 4; ++i) {
        if (base + i < nb) partial[base + i] = run;
        run += v[i];
    }
}

__global__ __launch_bounds__(256) void scan3_kernel(
        int* __restrict__ row_ptr, const int* __restrict__ partial,
        int* __restrict__ cursor, int N, int E) {
    int base = blockIdx.x * 1024 + threadIdx.x * 4;
    int off = partial[blockIdx.x];
    #pragma unroll
    for (int i = 0; i < 4; ++i) {
        int idx = base + i;
        if (idx < N) {
            int rp = row_ptr[idx] + off;
            row_ptr[idx] = rp;
            cursor[idx] = rp;
        }
    }
    if (blockIdx.x == 0 && threadIdx.x == 0) row_ptr[N] = E;
}

__global__ __launch_bounds__(256) void scatter_kernel(
        const int* __restrict__ src, const int* __restrict__ dst,
        int* __restrict__ cursor, int* __restrict__ csr_src, int E) {
    int e = blockIdx.x * 256 + threadIdx.x;
    if (e < E) {
        int p = atomicAdd(&cursor[dst[e]], 1);
        csr_src[p] = src[e];
    }
}

// ---- GEMM: Y[N,128] = (RELU?relu(X):X) @ W[128,128], 64-row x 64-col tiles ----
// grid = (ceil(N/64), 2). 256 threads: fg=t&15 (4 cols each), rg=t>>4 (4 rows each).
// W half staged in LDS (32 KB). X double-buffered in registers across k-steps.
template <bool RELU>
__global__ __launch_bounds__(256) void gemm64x64_kernel(
        const float* __restrict__ X, const float* __restrict__ W,
        float* __restrict__ Y, int N) {
    __shared__ float Ws[FEAT][64];   // 32 KB
    int t = threadIdx.x;
    int c0 = blockIdx.y * 64;
    for (int i = t; i < 2048; i += 256) {
        int r = i >> 4, c = (i & 15) << 2;
        *(float4*)&Ws[r][c] = *(const float4*)&W[r * FEAT + c0 + c];
    }
    __syncthreads();

    int f0 = (t & 15) * 4;
    int rbase = blockIdx.x * 64 + (t >> 4) * 4;
    const bool tail = (blockIdx.x == (int)gridDim.x - 1);

    float acc[4][4] = {};
    float4 xn[4];
    #pragma unroll
    for (int r = 0; r < 4; ++r) {
        int row = rbase + r;
        xn[r] = (!tail || row < N) ? *(const float4*)(X + (size_t)row * FEAT)
                                   : make_float4(0.f, 0.f, 0.f, 0.f);
    }

    for (int k0 = 0; k0 < FEAT; k0 += 4) {
        float4 xc[4];
        #pragma unroll
        for (int r = 0; r < 4; ++r) xc[r] = xn[r];
        if (k0 + 4 < FEAT) {
            #pragma unroll
            for (int r = 0; r < 4; ++r) {
                int row = rbase + r;
                xn[r] = (!tail || row < N)
                            ? *(const float4*)(X + (size_t)row * FEAT + k0 + 4)
                            : make_float4(0.f, 0.f, 0.f, 0.f);
            }
        }
        float4 wv0 = *(const float4*)&Ws[k0 + 0][f0];
        float4 wv1 = *(const float4*)&Ws[k0 + 1][f0];
        float4 wv2 = *(const float4*)&Ws[k0 + 2][f0];
        float4 wv3 = *(const float4*)&Ws[k0 + 3][f0];
        #pragma unroll
        for (int r = 0; r < 4; ++r) {
            float4 xv = xc[r];
            if (RELU) {
                xv.x = fmaxf(xv.x, 0.f); xv.y = fmaxf(xv.y, 0.f);
                xv.z = fmaxf(xv.z, 0.f); xv.w = fmaxf(xv.w, 0.f);
            }
            acc[r][0] += xv.x * wv0.x + xv.y * wv1.x + xv.z * wv2.x + xv.w * wv3.x;
            acc[r][1] += xv.x * wv0.y + xv.y * wv1.y + xv.z * wv2.y + xv.w * wv3.y;
            acc[r][2] += xv.x * wv0.z + xv.y * wv1.z + xv.z * wv2.z + xv.w * wv3.z;
            acc[r][3] += xv.x * wv0.w + xv.y * wv1.w + xv.z * wv2.w + xv.w * wv3.w;
        }
    }

    #pragma unroll
    for (int r = 0; r < 4; ++r) {
        int row = rbase + r;
        if (!tail || row < N)
            *(float4*)(Y + (size_t)row * FEAT + c0 + f0) =
                make_float4(acc[r][0], acc[r][1], acc[r][2], acc[r][3]);
    }
}

// ---- CSR gather: A[d] = sum_{s in N(d)} H[s]*dinv[s]*dinv[d] + H[d]*dinv[d]^2 + b ----
// One wave per node (64 lanes x float2 = 128 feats). 4 nodes per block.
__global__ __launch_bounds__(256) void gather_kernel(
        const int* __restrict__ row_ptr, const int* __restrict__ csr_src,
        const float* __restrict__ dinv, const float* __restrict__ H,
        const float* __restrict__ bias, float* __restrict__ A, int N) {
    int node = blockIdx.x * 4 + (threadIdx.x >> 6);
    if (node >= N) return;
    int lane = threadIdx.x & 63;
    const float2* H2 = (const float2*)H;
    float di = dinv[node];
    float2 b2 = ((const float2*)bias)[lane];
    float2 hs = H2[(size_t)node * 64 + lane];
    float2 acc;
    acc.x = hs.x * di * di + b2.x;
    acc.y = hs.y * di * di + b2.y;

    int j = row_ptr[node], end = row_ptr[node + 1];
    for (; j + 4 <= end; j += 4) {
        int s0 = csr_src[j + 0], s1 = csr_src[j + 1];
        int s2 = csr_src[j + 2], s3 = csr_src[j + 3];
        float w0 = dinv[s0] * di, w1 = dinv[s1] * di;
        float w2 = dinv[s2] * di, w3 = dinv[s3] * di;
        float2 h0 = H2[(size_t)s0 * 64 + lane];
        float2 h1 = H2[(size_t)s1 * 64 + lane];
        float2 h2 = H2[(size_t)s2 * 64 + lane];
        float2 h3 = H2[(size_t)s3 * 64 + lane];
        acc.x += h0.x * w0 + h1.x * w1 + h2.x * w2 + h3.x * w3;
        acc.y += h0.y * w0 + h1.y * w1 + h2.y * w2 + h3.y * w3;
    }
    for (; j < end; ++j) {
        int s = csr_src[j];
        float w = dinv[s] * di;
        float2 h = H2[(size_t)s * 64 + lane];
        acc.x += h.x * w;
        acc.y += h.y * w;
    }
    ((float2*)A)[(size_t)node * 64 + lane] = acc;
}

// ---- logits = relu(H)@Wout[128,64] + bout ; log_softmax across 64 lanes ----
__global__ __launch_bounds__(256) void final_kernel(
        const float* __restrict__ H, const float* __restrict__ Wout,
        const float* __restrict__ bout, float* __restrict__ out, int N) {
    __shared__ float Ws[FEAT][OUTF];   // 32 KB
    int t = threadIdx.x;
    for (int i = t; i < FEAT * OUTF; i += 256)
        Ws[i >> 6][i & 63] = Wout[i];
    __syncthreads();

    int wave = t >> 6;
    int lane = t & 63;
    float bj = bout[lane];
    int rbase = blockIdx.x * 16 + wave * 4;

    for (int r = 0; r < 4; ++r) {
        int row = rbase + r;
        if (row >= N) continue;              // wave-uniform branch
        const float4* h4 = (const float4*)(H + (size_t)row * FEAT);
        float acc = bj;
        #pragma unroll
        for (int k4 = 0; k4 < FEAT / 4; ++k4) {
            float4 hv = h4[k4];
            hv.x = fmaxf(hv.x, 0.f); hv.y = fmaxf(hv.y, 0.f);
            hv.z = fmaxf(hv.z, 0.f); hv.w = fmaxf(hv.w, 0.f);
            acc += hv.x * Ws[4 * k4 + 0][lane] + hv.y * Ws[4 * k4 + 1][lane]
                 + hv.z * Ws[4 * k4 + 2][lane] + hv.w * Ws[4 * k4 + 3][lane];
        }
        float m = acc;
        #pragma unroll
        for (int o = 32; o > 0; o >>= 1) m = fmaxf(m, __shfl_xor(m, o));
        float ev = __expf(acc - m);
        float s = ev;
        #pragma unroll
        for (int o = 32; o > 0; o >>= 1) s += __shfl_xor(s, o);
        out[(size_t)row * OUTF + lane] = acc - m - __logf(s);
    }
}

extern "C" void kernel_launch(void* const* d_in, const int* in_sizes, int n_in,
                              void* d_out, int out_size, void* d_ws, size_t ws_size,
                              hipStream_t stream) {
    const float* x    = (const float*)d_in[0];
    const int*   ei   = (const int*)  d_in[1];
    const float* W1   = (const float*)d_in[2];
    const float* b1   = (const float*)d_in[3];
    const float* W2   = (const float*)d_in[4];
    const float* b2   = (const float*)d_in[5];
    const float* Wout = (const float*)d_in[6];
    const float* bout = (const float*)d_in[7];
    float* out = (float*)d_out;

    int N = in_sizes[0] / FEAT;
    int E = in_sizes[1] / 2;
    const int* srcp = ei;
    const int* dstp = ei + E;

    char* ws = (char*)d_ws;
    float* Bh     = (float*)ws;                      // N*128 f
    float* Ba     = Bh + (size_t)N * FEAT;           // N*128 f
    int*   degi   = (int*)(Ba + (size_t)N * FEAT);   // N
    float* dinv   = (float*)(degi + N);              // N
    int*   rowp   = (int*)(dinv + N);                // N+1
    int*   cursor = rowp + N + 1;                    // N
    int*   partial= cursor + N;                      // 1024
    int*   csrsrc = partial + 1024;                  // E

    int nb = (N + 1023) / 1024;

    hipMemsetAsync(degi, 0, (size_t)N * sizeof(int), stream);
    deg_int_kernel<<<(E + 255) / 256, 256, 0, stream>>>(dstp, degi, E);
    dinv_kernel<<<(N + 255) / 256, 256, 0, stream>>>(degi, dinv, N);
    scan1_kernel<<<nb, 256, 0, stream>>>(degi, rowp, partial, N);
    scan2_kernel<<<1, 256, 0, stream>>>(partial, nb);
    scan3_kernel<<<nb, 256, 0, stream>>>(rowp, partial, cursor, N, E);
    scatter_kernel<<<(E + 255) / 256, 256, 0, stream>>>(srcp, dstp, cursor, csrsrc, E);

    dim3 ggrid((N + 63) / 64, 2);

    // Layer 1
    gemm64x64_kernel<false><<<ggrid, 256, 0, stream>>>(x, W1, Bh, N);
    gather_kernel<<<(N + 3) / 4, 256, 0, stream>>>(rowp, csrsrc, dinv, Bh, b1, Ba, N);

    // Layer 2
    gemm64x64_kernel<true><<<ggrid, 256, 0, stream>>>(Ba, W2, Bh, N);
    gather_kernel<<<(N + 3) / 4, 256, 0, stream>>>(rowp, csrsrc, dinv, Bh, b2, Ba, N);

    // Output layer + log_softmax
    final_kernel<<<(N + 15) / 16, 256, 0, stream>>>(Ba, Wout, bout, out, N);
}

// Round 3
// 536.650 us; speedup vs baseline: 3.7471x; 1.4796x over previous
//
#include <hip/hip_runtime.h>
#include <hip/hip_bf16.h>

// 3-layer GCN. Round 3: bf16 MFMA GEMMs + bf16 hidden storage (halves gather
// traffic). CSR build unchanged.
//
//   degi histogram -> dinv ; row_ptr scan ; csr scatter
//   W1,W2 -> bf16 transposed (W_t[n][k]) once per launch
//   L1: Bh = bf16( x@W1 )                      (MFMA, fp32 x converted in-flight)
//       Ba = bf16relu( gather(Bh) + Bh*dinv^2 + b1 )
//   L2: Bh = bf16( Ba@W2 )                     (MFMA)
//       Ba = bf16relu( gather(Bh) + Bh*dinv^2 + b2 )
//   OUT: logits = Ba@Wout + bout ; log_softmax (fp32)

#define FEAT 128
#define OUTF 64

typedef __attribute__((ext_vector_type(8))) short short8;
typedef __attribute__((ext_vector_type(4))) float f32x4;

__device__ __forceinline__ unsigned short bf16_rn(float f) {
    unsigned int u = __float_as_uint(f);
    u += 0x7FFFu + ((u >> 16) & 1u);   // round-to-nearest-even
    return (unsigned short)(u >> 16);
}
__device__ __forceinline__ float bf16_lo(unsigned int u) { return __uint_as_float(u << 16); }
__device__ __forceinline__ float bf16_hi(unsigned int u) { return __uint_as_float(u & 0xFFFF0000u); }

// ---------------- CSR build ----------------
__global__ __launch_bounds__(256) void deg_int_kernel(
        const int* __restrict__ dst, int* __restrict__ degi, int E) {
    int e = blockIdx.x * 256 + threadIdx.x;
    if (e < E) atomicAdd(&degi[dst[e]], 1);
}

__global__ __launch_bounds__(256) void dinv_kernel(
        const int* __restrict__ degi, float* __restrict__ dinv, int N) {
    int i = blockIdx.x * 256 + threadIdx.x;
    if (i < N) dinv[i] = rsqrtf((float)degi[i] + 1.0f);
}

__global__ __launch_bounds__(256) void scan1_kernel(
        const int* __restrict__ degi, int* __restrict__ row_ptr,
        int* __restrict__ partial, int N) {
    int t = threadIdx.x;
    int base = blockIdx.x * 1024 + t * 4;
    int v[4];
    #pragma unroll
    for (int i = 0; i < 4; ++i) v[i] = (base + i < N) ? degi[base + i] : 0;
    int local = v[0] + v[1] + v[2] + v[3];
    int lane = t & 63, wv = t >> 6;
    int x = local;
    #pragma unroll
    for (int o = 1; o < 64; o <<= 1) {
        int y = __shfl_up(x, o);
        if (lane >= o) x += y;
    }
    __shared__ int wsum[4];
    if (lane == 63) wsum[wv] = x;
    __syncthreads();
    int woff = 0;
    for (int i = 0; i < wv; ++i) woff += wsum[i];
    int run = woff + x - local;
    #pragma unroll
    for (int i = 0; i < 4; ++i) {
        if (base + i < N) row_ptr[base + i] = run;
        run += v[i];
    }
    if (t == 0) partial[blockIdx.x] = wsum[0] + wsum[1] + wsum[2] + wsum[3];
}

__global__ __launch_bounds__(256) void scan2_kernel(int* __restrict__ partial, int nb) {
    int t = threadIdx.x;
    int base = t * 4;
    int v[4];
    #pragma unroll
    for (int i = 0; i < 4; ++i) v[i] = (base + i < nb) ? partial[base + i] : 0;
    int local = v[0] + v[1] + v[2] + v[3];
    int lane = t & 63, wv = t >> 6;
    int x = local;
    #pragma unroll
    for (int o = 1; o < 64; o <<= 1) {
        int y = __shfl_up(x, o);
        if (lane >= o) x += y;
    }
    __shared__ int wsum[4];
    if (lane == 63) wsum[wv] = x;
    __syncthreads();
    int woff = 0;
    for (int i = 0; i < wv; ++i) woff += wsum[i];
    int run = woff + x - local;
    #pragma unroll
    for (int i = 0; i < 4; ++i) {
        if (base + i < nb) partial[base + i] = run;
        run += v[i];
    }
}

__global__ __launch_bounds__(256) void scan3_kernel(
        int* __restrict__ row_ptr, const int* __restrict__ partial,
        int* __restrict__ cursor, int N, int E) {
    int base = blockIdx.x * 1024 + threadIdx.x * 4;
    int off = partial[blockIdx.x];
    #pragma unroll
    for (int i = 0; i < 4; ++i) {
        int idx = base + i;
        if (idx < N) {
            int rp = row_ptr[idx] + off;
            row_ptr[idx] = rp;
            cursor[idx] = rp;
        }
    }
    if (blockIdx.x == 0 && threadIdx.x == 0) row_ptr[N] = E;
}

__global__ __launch_bounds__(256) void scatter_kernel(
        const int* __restrict__ src, const int* __restrict__ dst,
        int* __restrict__ cursor, int* __restrict__ csr_src, int E) {
    int e = blockIdx.x * 256 + threadIdx.x;
    if (e < E) {
        int p = atomicAdd(&cursor[dst[e]], 1);
        csr_src[p] = src[e];
    }
}

// ---------------- weight convert: W[k][n] fp32 -> Wt[n][k] bf16 ----------------
__global__ __launch_bounds__(256) void convw_kernel(
        const float* __restrict__ W, __hip_bfloat16* __restrict__ Wt, int K, int Ncol) {
    int idx = blockIdx.x * 256 + threadIdx.x;
    if (idx < K * Ncol) {
        int n = idx / K, k = idx - n * K;
        ((unsigned short*)Wt)[idx] = bf16_rn(W[k * Ncol + n]);
    }
}

// ---------------- MFMA GEMM: Y[N][128] = X[N][128] @ W, Wt[n][k] bf16 ----------------
// 256 thr = 4 waves; wave w handles 16 rows (tile rt = blk*4 + w). 16x16x32 MFMA.
// W staged in LDS (padded stride 136 shorts = 272 B, 16B-aligned rows, 2-way banks).
template <bool IN_FP32>
__global__ __launch_bounds__(256) void mfma_gemm_kernel(
        const void* __restrict__ Xv, const __hip_bfloat16* __restrict__ Wt,
        __hip_bfloat16* __restrict__ Y, int N) {
    __shared__ short Ws[FEAT][136];
    int t = threadIdx.x;
    for (int i = t; i < FEAT * 16; i += 256) {
        int n = i >> 4, c = i & 15;
        *(uint4*)&Ws[n][c * 8] = *(const uint4*)((const unsigned short*)Wt + n * FEAT + c * 8);
    }
    __syncthreads();

    int wave = t >> 6, lane = t & 63;
    int m = lane & 15, quad = lane >> 4;
    int rbase = (blockIdx.x * 4 + wave) * 16;
    if (rbase >= N) return;                 // wave-uniform
    int row = rbase + m;
    bool rok = row < N;

    f32x4 acc[8];
    #pragma unroll
    for (int nt = 0; nt < 8; ++nt) acc[nt] = (f32x4){0.f, 0.f, 0.f, 0.f};

    #pragma unroll
    for (int ks = 0; ks < 4; ++ks) {
        short8 a;
        if (IN_FP32) {
            const float* X = (const float*)Xv;
            float xs[8];
            if (rok) {
                float4 x0 = *(const float4*)(X + (size_t)row * FEAT + ks * 32 + quad * 8);
                float4 x1 = *(const float4*)(X + (size_t)row * FEAT + ks * 32 + quad * 8 + 4);
                xs[0] = x0.x; xs[1] = x0.y; xs[2] = x0.z; xs[3] = x0.w;
                xs[4] = x1.x; xs[5] = x1.y; xs[6] = x1.z; xs[7] = x1.w;
            } else {
                #pragma unroll
                for (int j = 0; j < 8; ++j) xs[j] = 0.f;
            }
            #pragma unroll
            for (int j = 0; j < 8; ++j) a[j] = (short)bf16_rn(xs[j]);
        } else {
            const unsigned short* X = (const unsigned short*)Xv;
            if (rok)
                a = *(const short8*)(X + (size_t)row * FEAT + ks * 32 + quad * 8);
            else {
                #pragma unroll
                for (int j = 0; j < 8; ++j) a[j] = 0;
            }
        }
        #pragma unroll
        for (int nt = 0; nt < 8; ++nt) {
            short8 b = *(const short8*)&Ws[nt * 16 + m][ks * 32 + quad * 8];
            acc[nt] = __builtin_amdgcn_mfma_f32_16x16x32_bf16(a, b, acc[nt], 0, 0, 0);
        }
    }

    unsigned short* Yo = (unsigned short*)Y;
    #pragma unroll
    for (int nt = 0; nt < 8; ++nt) {
        #pragma unroll
        for (int r = 0; r < 4; ++r) {
            int ro = rbase + quad * 4 + r;
            if (ro < N)
                Yo[(size_t)ro * FEAT + nt * 16 + m] = bf16_rn(acc[nt][r]);
        }
    }
}

// ---------------- CSR gather (bf16 H): A[d] = relu(sum H[s]*w + H[d]*di^2 + b) ----------------
__global__ __launch_bounds__(256) void gather_kernel(
        const int* __restrict__ row_ptr, const int* __restrict__ csr_src,
        const float* __restrict__ dinv, const __hip_bfloat16* __restrict__ H,
        const float* __restrict__ bias, __hip_bfloat16* __restrict__ A, int N) {
    int node = blockIdx.x * 4 + (threadIdx.x >> 6);
    if (node >= N) return;
    int lane = threadIdx.x & 63;
    const unsigned int* H2 = (const unsigned int*)H;
    float di = dinv[node];
    float2 b2 = ((const float2*)bias)[lane];
    unsigned int hu = H2[(size_t)node * 64 + lane];
    float ax = bf16_lo(hu) * di * di + b2.x;
    float ay = bf16_hi(hu) * di * di + b2.y;

    int j = row_ptr[node], end = row_ptr[node + 1];
    for (; j + 4 <= end; j += 4) {
        int s0 = csr_src[j + 0], s1 = csr_src[j + 1];
        int s2 = csr_src[j + 2], s3 = csr_src[j + 3];
        float w0 = dinv[s0] * di, w1 = dinv[s1] * di;
        float w2 = dinv[s2] * di, w3 = dinv[s3] * di;
        unsigned int u0 = H2[(size_t)s0 * 64 + lane];
        unsigned int u1 = H2[(size_t)s1 * 64 + lane];
        unsigned int u2 = H2[(size_t)s2 * 64 + lane];
        unsigned int u3 = H2[(size_t)s3 * 64 + lane];
        ax += bf16_lo(u0) * w0 + bf16_lo(u1) * w1 + bf16_lo(u2) * w2 + bf16_lo(u3) * w3;
        ay += bf16_hi(u0) * w0 + bf16_hi(u1) * w1 + bf16_hi(u2) * w2 + bf16_hi(u3) * w3;
    }
    for (; j < end; ++j) {
        int s = csr_src[j];
        float w = dinv[s] * di;
        unsigned int u = H2[(size_t)s * 64 + lane];
        ax += bf16_lo(u) * w;
        ay += bf16_hi(u) * w;
    }
    // fused relu + bf16 pack
    ax = fmaxf(ax, 0.f); ay = fmaxf(ay, 0.f);
    unsigned int packed = (unsigned int)bf16_rn(ax) | ((unsigned int)bf16_rn(ay) << 16);
    ((unsigned int*)A)[(size_t)node * 64 + lane] = packed;
}

// ---------------- final: logits = H@Wout + bout (H already relu'd bf16) ; log_softmax ----------------
__global__ __launch_bounds__(256) void final_kernel(
        const __hip_bfloat16* __restrict__ H, const float* __restrict__ Wout,
        const float* __restrict__ bout, float* __restrict__ out, int N) {
    __shared__ float Ws[FEAT][OUTF];   // 32 KB
    int t = threadIdx.x;
    for (int i = t; i < FEAT * OUTF; i += 256)
        Ws[i >> 6][i & 63] = Wout[i];
    __syncthreads();

    int wave = t >> 6;
    int lane = t & 63;
    float bj = bout[lane];
    int rbase = blockIdx.x * 16 + wave * 4;

    for (int r = 0; r < 4; ++r) {
        int row = rbase + r;
        if (row >= N) continue;              // wave-uniform
        const uint4* h16 = (const uint4*)((const unsigned short*)H + (size_t)row * FEAT);
        float acc = bj;
        #pragma unroll
        for (int i = 0; i < 8; ++i) {
            uint4 q = h16[i];
            acc += bf16_lo(q.x) * Ws[8 * i + 0][lane] + bf16_hi(q.x) * Ws[8 * i + 1][lane]
                 + bf16_lo(q.y) * Ws[8 * i + 2][lane] + bf16_hi(q.y) * Ws[8 * i + 3][lane]
                 + bf16_lo(q.z) * Ws[8 * i + 4][lane] + bf16_hi(q.z) * Ws[8 * i + 5][lane]
                 + bf16_lo(q.w) * Ws[8 * i + 6][lane] + bf16_hi(q.w) * Ws[8 * i + 7][lane];
        }
        float mx = acc;
        #pragma unroll
        for (int o = 32; o > 0; o >>= 1) mx = fmaxf(mx, __shfl_xor(mx, o));
        float ev = __expf(acc - mx);
        float s = ev;
        #pragma unroll
        for (int o = 32; o > 0; o >>= 1) s += __shfl_xor(s, o);
        out[(size_t)row * OUTF + lane] = acc - mx - __logf(s);
    }
}

extern "C" void kernel_launch(void* const* d_in, const int* in_sizes, int n_in,
                              void* d_out, int out_size, void* d_ws, size_t ws_size,
                              hipStream_t stream) {
    const float* x    = (const float*)d_in[0];
    const int*   ei   = (const int*)  d_in[1];
    const float* W1   = (const float*)d_in[2];
    const float* b1   = (const float*)d_in[3];
    const float* W2   = (const float*)d_in[4];
    const float* b2   = (const float*)d_in[5];
    const float* Wout = (const float*)d_in[6];
    const float* bout = (const float*)d_in[7];
    float* out = (float*)d_out;

    int N = in_sizes[0] / FEAT;
    int E = in_sizes[1] / 2;
    const int* srcp = ei;
    const int* dstp = ei + E;

    char* ws = (char*)d_ws;
    __hip_bfloat16* Bh  = (__hip_bfloat16*)ws;                    // N*128 bf16
    __hip_bfloat16* Ba  = Bh + (size_t)N * FEAT;                  // N*128 bf16
    __hip_bfloat16* W1t = Ba + (size_t)N * FEAT;                  // 128*128 bf16
    __hip_bfloat16* W2t = W1t + FEAT * FEAT;                      // 128*128 bf16
    int*   degi    = (int*)(W2t + FEAT * FEAT);                   // N
    float* dinv    = (float*)(degi + N);                          // N
    int*   rowp    = (int*)(dinv + N);                            // N+1
    int*   cursor  = rowp + N + 1;                                // N
    int*   partial = cursor + N;                                  // 1024
    int*   csrsrc  = partial + 1024;                              // E

    int nb = (N + 1023) / 1024;

    hipMemsetAsync(degi, 0, (size_t)N * sizeof(int), stream);
    deg_int_kernel<<<(E + 255) / 256, 256, 0, stream>>>(dstp, degi, E);
    dinv_kernel<<<(N + 255) / 256, 256, 0, stream>>>(degi, dinv, N);
    scan1_kernel<<<nb, 256, 0, stream>>>(degi, rowp, partial, N);
    scan2_kernel<<<1, 256, 0, stream>>>(partial, nb);
    scan3_kernel<<<nb, 256, 0, stream>>>(rowp, partial, cursor, N, E);
    scatter_kernel<<<(E + 255) / 256, 256, 0, stream>>>(srcp, dstp, cursor, csrsrc, E);

    convw_kernel<<<(FEAT * FEAT + 255) / 256, 256, 0, stream>>>(W1, W1t, FEAT, FEAT);
    convw_kernel<<<(FEAT * FEAT + 255) / 256, 256, 0, stream>>>(W2, W2t, FEAT, FEAT);

    int ggrid = (N + 63) / 64;

    // Layer 1
    mfma_gemm_kernel<true><<<ggrid, 256, 0, stream>>>(x, W1t, Bh, N);
    gather_kernel<<<(N + 3) / 4, 256, 0, stream>>>(rowp, csrsrc, dinv, Bh, b1, Ba, N);

    // Layer 2
    mfma_gemm_kernel<false><<<ggrid, 256, 0, stream>>>(Ba, W2t, Bh, N);
    gather_kernel<<<(N + 3) / 4, 256, 0, stream>>>(rowp, csrsrc, dinv, Bh, b2, Ba, N);

    // Output layer + log_softmax
    final_kernel<<<(N + 15) / 16, 256, 0, stream>>>(Ba, Wout, bout, out, N);
}